// Round 12
// baseline (266.804 us; speedup 1.0000x reference)
//
#include <hip/hip_runtime.h>

#define BB 4
#define NN 2048
#define DD 1024
#define HH 16
#define DHH 64
#define MM (BB*NN)   // 8192
#define QS 3072

typedef unsigned short u16;
typedef __attribute__((ext_vector_type(8))) short short8;
typedef __attribute__((ext_vector_type(4))) float floatx4;

#if __has_builtin(__builtin_amdgcn_exp2f)
#define EXP2F __builtin_amdgcn_exp2f
#else
#define EXP2F exp2f
#endif

__device__ __forceinline__ u16 f2bf(float f) {  // RNE
  union { float f; unsigned u; } v; v.f = f;
  unsigned u = v.u;
  return (u16)((u + 0x7fffu + ((u >> 16) & 1u)) >> 16);
}
__device__ __forceinline__ float bf2f(u16 h) {
  union { unsigned u; float f; } v; v.u = ((unsigned)h) << 16;
  return v.f;
}
__device__ __forceinline__ unsigned fbits(float f) {
  union { float f; unsigned u; } v; v.f = f; return v.u;
}
// pack two f32 -> (lo bf16 | hi bf16 << 16) by TRUNCATION (1 v_perm).
// Bias cancels: softmax denominator (ones-MFMA) uses the same truncated values.
__device__ __forceinline__ unsigned pkbf(float lo, float hi) {
#if __has_builtin(__builtin_amdgcn_perm)
  return __builtin_amdgcn_perm(fbits(hi), fbits(lo), 0x07060302u);
#else
  return (fbits(lo) >> 16) | (fbits(hi) & 0xffff0000u);
#endif
}
__device__ __forceinline__ void gll16(const u16* g, u16* l) {
  __builtin_amdgcn_global_load_lds((const __attribute__((address_space(1))) unsigned int*)g,
                                   (__attribute__((address_space(3))) unsigned int*)l, 16, 0, 0);
}
// conflict-free 128x32 tile: row-pairs in 128B lines, chunk XOR-swizzled.
__device__ __forceinline__ int toff(int row, int kc) {
  int pr = row >> 1;
  int c = (((row & 1) << 2) + kc) ^ (pr & 7);
  return pr * 64 + c * 8;
}

#define SOFTMAX_SCALE 0.18033688f    // 0.125 * log2(e)
#define SOFTMAX_BIAS  -28.8539008f   // fixed-max offset (20 * log2(e))

// ---------------- fp32 -> bf16 elementwise convert ----------------
__global__ __launch_bounds__(256) void cvt_kernel(const float* __restrict__ in,
                                                  u16* __restrict__ out, int n) {
  int i = (blockIdx.x * 256 + threadIdx.x) * 4;
  if (i >= n) return;
  float4 v = *(const float4*)(in + i);
  u16 o[4] = {f2bf(v.x), f2bf(v.y), f2bf(v.z), f2bf(v.w)};
  *(uint2*)(out + i) = *(uint2*)o;
}

// ---------------- merged transpose-convert: Wq, Wkv, Wout in one launch ----------------
__global__ __launch_bounds__(256) void tcvt3_kernel(const float* __restrict__ Wq,
                                                    const float* __restrict__ Wkv,
                                                    const float* __restrict__ Wout,
                                                    u16* __restrict__ WT,
                                                    u16* __restrict__ WoutT) {
  __shared__ float t[64][65];
  int bx = blockIdx.x;
  const float* src;
  u16* dst;
  int C, c0;
  if (bx < 16)      { src = Wq;   dst = WT;                       C = 1024; c0 = bx * 64; }
  else if (bx < 48) { src = Wkv;  dst = WT + (size_t)DD * DD;     C = 2048; c0 = (bx - 16) * 64; }
  else              { src = Wout; dst = WoutT;                    C = 1024; c0 = (bx - 48) * 64; }
  const int R = 1024;
  int r0 = blockIdx.y * 64;
  int tid = threadIdx.x;
#pragma unroll
  for (int i = 0; i < 16; ++i) {
    int lin = i * 256 + tid;
    int rr = lin >> 6, cc = lin & 63;
    t[rr][cc] = src[(size_t)(r0 + rr) * C + c0 + cc];
  }
  __syncthreads();
#pragma unroll
  for (int i = 0; i < 16; ++i) {
    int lin = i * 256 + tid;
    int rr = lin >> 6, cc = lin & 63;
    dst[(size_t)(c0 + rr) * R + r0 + cc] = f2bf(t[cc][rr]);
  }
}

// ---------------- packed rope table: tab4[n*32+d] = (cos d, sin d, cos d+32, sin d+32) ----------------
__global__ __launch_bounds__(256) void rope_tab_kernel(const float* __restrict__ rot,
                                                       float4* __restrict__ tab4) {
  int i = blockIdx.x * 256 + threadIdx.x;  // n*32+d, d in [0,32)
  int n = i >> 5, d = i & 31;
  float p0 = rot[n * 64 + d];
  float p1 = rot[n * 64 + d + 32];
  float s0, c0, s1, c1;
  __sincosf(p0, &s0, &c0);
  __sincosf(p1, &s1, &c1);
  tab4[i] = make_float4(c0, s0, c1, s1);
}

// ---------------- fused QKV GEMM: pipelined staging + conflict-free LDS ----------------
// q (pre-scaled by SOFTMAX_SCALE),k -> dense [bh][n][64]; v -> vt[bh][n/64][64d][64tok].
__global__ __launch_bounds__(256, 4) void gemm_qkv(const u16* __restrict__ A,
                                                   const u16* __restrict__ Bt,
                                                   u16* __restrict__ qd,
                                                   u16* __restrict__ kd,
                                                   u16* __restrict__ vt,
                                                   const float4* __restrict__ tab4) {
  const int K = DD;
  __shared__ __align__(16) u16 lds[16384];
  int tid = threadIdx.x;
  int wave = tid >> 6, lane = tid & 63;
  int q4 = lane >> 4, l16 = lane & 15;
  int m0 = blockIdx.y * 128, n0 = blockIdx.x * 128;
  int wm = (wave >> 1) * 64, wn = (wave & 1) * 64;

  const u16* Ag = A + (size_t)m0 * K;
  const u16* Bg = Bt + (size_t)n0 * K;
  int o1 = tid, o2 = tid + 256;
  int pr1 = o1 >> 3, c1 = (o1 & 7) ^ (pr1 & 7);
  int row1 = pr1 * 2 + (c1 >> 2), kc1 = (c1 & 3) * 8;
  int pr2 = o2 >> 3, c2 = (o2 & 7) ^ (pr2 & 7);
  int row2 = pr2 * 2 + (c2 >> 2), kc2 = (c2 & 3) * 8;
  int d1 = wave * 512, d2 = 2048 + wave * 512;

  int foA[4], foB[4];
#pragma unroll
  for (int i = 0; i < 4; ++i) {
    foA[i] = toff(wm + i * 16 + l16, q4);
    foB[i] = toff(wn + i * 16 + l16, q4);
  }

  floatx4 acc[4][4];
#pragma unroll
  for (int mi = 0; mi < 4; ++mi)
#pragma unroll
    for (int ni = 0; ni < 4; ++ni) acc[mi][ni] = (floatx4){0.f, 0.f, 0.f, 0.f};

  gll16(Ag + (size_t)row1 * K + kc1, lds + d1);
  gll16(Ag + (size_t)row2 * K + kc2, lds + d2);
  gll16(Bg + (size_t)row1 * K + kc1, lds + 8192 + d1);
  gll16(Bg + (size_t)row2 * K + kc2, lds + 8192 + d2);

  for (int k0 = 0, it = 0; k0 < K; k0 += 32, ++it) {
    int boff = (it & 1) * 4096;
    if (k0 + 32 < K) {
      int nboff = 4096 - boff;
      int kn = k0 + 32;
      gll16(Ag + (size_t)row1 * K + kn + kc1, lds + nboff + d1);
      gll16(Ag + (size_t)row2 * K + kn + kc2, lds + nboff + d2);
      gll16(Bg + (size_t)row1 * K + kn + kc1, lds + 8192 + nboff + d1);
      gll16(Bg + (size_t)row2 * K + kn + kc2, lds + 8192 + nboff + d2);
      __builtin_amdgcn_s_waitcnt(0x0F74);  // vmcnt(4)
    } else {
      __builtin_amdgcn_s_waitcnt(0x0F70);  // vmcnt(0)
    }
    __builtin_amdgcn_s_barrier();
    const u16* Ac = lds + boff;
    const u16* Bc = lds + 8192 + boff;
    short8 af[4], bfr[4];
#pragma unroll
    for (int i = 0; i < 4; ++i) {
      af[i]  = *(const short8*)(Ac + foA[i]);
      bfr[i] = *(const short8*)(Bc + foB[i]);
    }
#pragma unroll
    for (int mi = 0; mi < 4; ++mi)
#pragma unroll
      for (int ni = 0; ni < 4; ++ni)
        acc[mi][ni] = __builtin_amdgcn_mfma_f32_16x16x32_bf16(af[mi], bfr[ni], acc[mi][ni], 0, 0, 0);
    __builtin_amdgcn_s_barrier();
  }

  // ---- epilogue: rope (+ q pre-scale) + direct scalar stores ----
  int colbase = n0 + wn;
  int slot = colbase >> 10;              // 0=q, 1=k, 2=v
  int h = (colbase >> 6) & 15;
#pragma unroll
  for (int mi = 0; mi < 4; ++mi) {
    int mbase = m0 + wm + mi * 16 + q4 * 4;
    float vals[4][4];
    if (slot < 2) {
      float sc = slot ? 1.0f : SOFTMAX_SCALE;
#pragma unroll
      for (int r = 0; r < 4; ++r) {
        int n = (mbase + r) & (NN - 1);
#pragma unroll
        for (int ni = 0; ni < 2; ++ni) {
          int d0 = ni * 16 + l16;
          float4 cs = tab4[n * 32 + d0];
          float v0 = acc[mi][ni][r], v1 = acc[mi][ni + 2][r];
          vals[ni][r]     = (v0 * cs.x - v1 * cs.y) * sc;
          vals[ni + 2][r] = (v1 * cs.z + v0 * cs.w) * sc;
        }
      }
      u16* dst = slot ? kd : qd;
#pragma unroll
      for (int ni = 0; ni < 4; ++ni)
#pragma unroll
        for (int r = 0; r < 4; ++r) {
          int m = mbase + r;
          dst[((size_t)((m >> 11) * HH + h) * NN + (m & (NN - 1))) * 64 + ni * 16 + l16] =
              f2bf(vals[ni][r]);
        }
    } else {
#pragma unroll
      for (int ni = 0; ni < 4; ++ni) {
        int d = ni * 16 + l16;
#pragma unroll
        for (int r = 0; r < 4; ++r) {
          int m = mbase + r;
          int nn = m & (NN - 1);
          vt[(size_t)((m >> 11) * HH + h) * (NN * 64) + (nn >> 6) * 4096 + d * 64 + (nn & 63)] =
              f2bf(acc[mi][ni][r]);
        }
      }
    }
  }
}

// ---------------- bf16 GEMM (pipelined): C[M,N] = A @ Bt^T + bias (fp32 out) ----------------
__global__ __launch_bounds__(256, 4) void gemm_out(const u16* __restrict__ A,
                                                   const u16* __restrict__ Bt,
                                                   float* __restrict__ Cout,
                                                   const float* __restrict__ bias,
                                                   int M, int N, int K) {
  __shared__ __align__(16) u16 lds[16384];
  int tid = threadIdx.x;
  int wave = tid >> 6, lane = tid & 63;
  int q4 = lane >> 4, l16 = lane & 15;
  int m0 = blockIdx.y * 128, n0 = blockIdx.x * 128;
  int wm = (wave >> 1) * 64, wn = (wave & 1) * 64;

  const u16* Ag = A + (size_t)m0 * K;
  const u16* Bg = Bt + (size_t)n0 * K;
  int o1 = tid, o2 = tid + 256;
  int pr1 = o1 >> 3, c1 = (o1 & 7) ^ (pr1 & 7);
  int row1 = pr1 * 2 + (c1 >> 2), kc1 = (c1 & 3) * 8;
  int pr2 = o2 >> 3, c2 = (o2 & 7) ^ (pr2 & 7);
  int row2 = pr2 * 2 + (c2 >> 2), kc2 = (c2 & 3) * 8;
  int d1 = wave * 512, d2 = 2048 + wave * 512;

  int foA[4], foB[4];
#pragma unroll
  for (int i = 0; i < 4; ++i) {
    foA[i] = toff(wm + i * 16 + l16, q4);
    foB[i] = toff(wn + i * 16 + l16, q4);
  }

  floatx4 acc[4][4];
#pragma unroll
  for (int mi = 0; mi < 4; ++mi)
#pragma unroll
    for (int ni = 0; ni < 4; ++ni) acc[mi][ni] = (floatx4){0.f, 0.f, 0.f, 0.f};

  gll16(Ag + (size_t)row1 * K + kc1, lds + d1);
  gll16(Ag + (size_t)row2 * K + kc2, lds + d2);
  gll16(Bg + (size_t)row1 * K + kc1, lds + 8192 + d1);
  gll16(Bg + (size_t)row2 * K + kc2, lds + 8192 + d2);

  for (int k0 = 0, it = 0; k0 < K; k0 += 32, ++it) {
    int boff = (it & 1) * 4096;
    if (k0 + 32 < K) {
      int nboff = 4096 - boff;
      int kn = k0 + 32;
      gll16(Ag + (size_t)row1 * K + kn + kc1, lds + nboff + d1);
      gll16(Ag + (size_t)row2 * K + kn + kc2, lds + nboff + d2);
      gll16(Bg + (size_t)row1 * K + kn + kc1, lds + 8192 + nboff + d1);
      gll16(Bg + (size_t)row2 * K + kn + kc2, lds + 8192 + nboff + d2);
      __builtin_amdgcn_s_waitcnt(0x0F74);  // vmcnt(4)
    } else {
      __builtin_amdgcn_s_waitcnt(0x0F70);  // vmcnt(0)
    }
    __builtin_amdgcn_s_barrier();
    const u16* Ac = lds + boff;
    const u16* Bc = lds + 8192 + boff;
    short8 af[4], bfr[4];
#pragma unroll
    for (int i = 0; i < 4; ++i) {
      af[i]  = *(const short8*)(Ac + foA[i]);
      bfr[i] = *(const short8*)(Bc + foB[i]);
    }
#pragma unroll
    for (int mi = 0; mi < 4; ++mi)
#pragma unroll
      for (int ni = 0; ni < 4; ++ni)
        acc[mi][ni] = __builtin_amdgcn_mfma_f32_16x16x32_bf16(af[mi], bfr[ni], acc[mi][ni], 0, 0, 0);
    __builtin_amdgcn_s_barrier();
  }

#pragma unroll
  for (int ni = 0; ni < 4; ++ni) {
    int col = n0 + wn + ni * 16 + l16;
    float bval = bias[col];
#pragma unroll
    for (int mi = 0; mi < 4; ++mi) {
#pragma unroll
      for (int r = 0; r < 4; ++r) {
        int row = m0 + wm + mi * 16 + q4 * 4 + r;
        Cout[(size_t)row * N + col] = acc[mi][ni][r] + bval;
      }
    }
  }
}

// ---------------- flash attention v4: bias-in-accumulator, ones-MFMA lsum ----------------
__global__ __launch_bounds__(512, 4) void attn_kernel(const u16* __restrict__ qd,
                                                      const u16* __restrict__ kd,
                                                      const u16* __restrict__ vt,
                                                      u16* __restrict__ ao) {
  __shared__ __align__(16) u16 lds[16384];   // 32 KB

  int tid = threadIdx.x, wave = tid >> 6, lane = tid & 63;
  int q4 = lane >> 4, l16 = lane & 15;
  int qt = blockIdx.x, bh = blockIdx.y, b = bh >> 4, h = bh & 15;
  const u16* qbh = qd + (size_t)bh * NN * 64;
  const u16* kbh = kd + (size_t)bh * NN * 64;
  const u16* vbh = vt + (size_t)bh * NN * 64;   // tiles [n/64][64d][64tok]

  int srow = wave * 8 + (lane >> 3);
  int g = ((lane & 7) ^ ((lane >> 3) & 7)) * 8;
  // permuted K source row for destination LDS row srow
  int prow = ((srow >> 2) & 3) * 8 + ((srow >> 4) & 1) * 4 + (srow & 3) + ((srow >> 5) & 1) * 32;

  // ---- stage Q [256 x 64], read fragments, then reuse LDS ----
#pragma unroll
  for (int it = 0; it < 4; ++it)
    gll16(qbh + (size_t)(qt * 256 + it * 64 + srow) * 64 + g, lds + (it * 64 + wave * 8) * 64);
  __builtin_amdgcn_s_waitcnt(0x0F70);   // vmcnt(0)
  __builtin_amdgcn_s_barrier();

  short8 aq[2][2];
#pragma unroll
  for (int mi = 0; mi < 2; ++mi)
#pragma unroll
    for (int ks = 0; ks < 2; ++ks) {
      int row = wave * 32 + mi * 16 + l16;
      aq[mi][ks] = *(const short8*)(lds + row * 64 + (((ks * 4 + q4) ^ (row & 7)) * 8));
    }
  __builtin_amdgcn_s_waitcnt(0xC07F);   // lgkmcnt(0)
  __builtin_amdgcn_s_barrier();

  // preload tile 0
  gll16(kbh + (size_t)prow * 64 + g, lds + wave * 512);
  gll16(vbh + (size_t)srow * 64 + g, lds + 8192 + wave * 512);

  union { unsigned u[4]; short8 s8; } ones;
#pragma unroll
  for (int i = 0; i < 4; ++i) ones.u[i] = 0x3F803F80u;

  floatx4 lacc[2];
  floatx4 o[2][4];
#pragma unroll
  for (int mi = 0; mi < 2; ++mi) {
    lacc[mi] = (floatx4){0.f, 0.f, 0.f, 0.f};
#pragma unroll
    for (int di = 0; di < 4; ++di) o[mi][di] = (floatx4){0.f, 0.f, 0.f, 0.f};
  }

  for (int j0 = 0, itn = 0; j0 < NN; j0 += 64, ++itn) {
    int coff = (itn & 1) * 4096;
    if (j0 + 64 < NN) {
      int noff = 4096 - coff;
      gll16(kbh + (size_t)(j0 + 64 + prow) * 64 + g, lds + noff + wave * 512);
      gll16(vbh + (size_t)((j0 >> 6) + 1) * 4096 + srow * 64 + g, lds + 8192 + noff + wave * 512);
      __builtin_amdgcn_s_waitcnt(0x0F72);   // vmcnt(2)
    } else {
      __builtin_amdgcn_s_waitcnt(0x0F70);   // vmcnt(0)
    }
    __builtin_amdgcn_s_barrier();

    const u16* Kc = lds + coff;
    const u16* Vc = lds + 8192 + coff;

    // S^T = K Q'^T + BIAS
    floatx4 s[4][2];
#pragma unroll
    for (int kg = 0; kg < 4; ++kg)
#pragma unroll
      for (int mi = 0; mi < 2; ++mi)
        s[kg][mi] = (floatx4){SOFTMAX_BIAS, SOFTMAX_BIAS, SOFTMAX_BIAS, SOFTMAX_BIAS};
#pragma unroll
    for (int ks = 0; ks < 2; ++ks) {
      short8 kf[4];
#pragma unroll
      for (int kg = 0; kg < 4; ++kg) {
        int row = kg * 16 + l16;
        kf[kg] = *(const short8*)(Kc + row * 64 + (((ks * 4 + q4) ^ (row & 7)) * 8));
      }
#pragma unroll
      for (int kg = 0; kg < 4; ++kg)
#pragma unroll
        for (int mi = 0; mi < 2; ++mi)
          s[kg][mi] = __builtin_amdgcn_mfma_f32_16x16x32_bf16(kf[kg], aq[mi][ks], s[kg][mi], 0, 0, 0);
    }

    // exp2 + truncation pack (keys q4*8 + (kg&1)*4 + r + (kg>>1)*32)
    unsigned pk[4][2][2];
#pragma unroll
    for (int kg = 0; kg < 4; ++kg)
#pragma unroll
      for (int mi = 0; mi < 2; ++mi) {
        float e0 = EXP2F(s[kg][mi][0]);
        float e1 = EXP2F(s[kg][mi][1]);
        float e2 = EXP2F(s[kg][mi][2]);
        float e3 = EXP2F(s[kg][mi][3]);
        pk[kg][mi][0] = pkbf(e0, e1);
        pk[kg][mi][1] = pkbf(e2, e3);
      }

    // O^T += V^T P^T ; lsum via ones-MFMA
#pragma unroll
    for (int ks = 0; ks < 2; ++ks) {
      short8 vf[4];
#pragma unroll
      for (int di = 0; di < 4; ++di) {
        int row = di * 16 + l16;
        vf[di] = *(const short8*)(Vc + row * 64 + (((ks * 4 + q4) ^ (row & 7)) * 8));
      }
#pragma unroll
      for (int mi = 0; mi < 2; ++mi) {
        union { unsigned u[4]; short8 s8; } bw;
        bw.u[0] = pk[2 * ks][mi][0];
        bw.u[1] = pk[2 * ks][mi][1];
        bw.u[2] = pk[2 * ks + 1][mi][0];
        bw.u[3] = pk[2 * ks + 1][mi][1];
        lacc[mi] = __builtin_amdgcn_mfma_f32_16x16x32_bf16(ones.s8, bw.s8, lacc[mi], 0, 0, 0);
#pragma unroll
        for (int di = 0; di < 4; ++di)
          o[mi][di] = __builtin_amdgcn_mfma_f32_16x16x32_bf16(vf[di], bw.s8, o[mi][di], 0, 0, 0);
      }
    }
    __builtin_amdgcn_s_barrier();
  }

  float rinv[2];
#pragma unroll
  for (int mi = 0; mi < 2; ++mi) rinv[mi] = 1.0f / lacc[mi][0];

#pragma unroll
  for (int mi = 0; mi < 2; ++mi) {
    int qrow = qt * 256 + wave * 32 + mi * 16 + l16;
    size_t base = (size_t)(b * NN + qrow) * DD + h * DHH + q4 * 4;
#pragma unroll
    for (int di = 0; di < 4; ++di)
#pragma unroll
      for (int r = 0; r < 4; ++r)
        ao[base + di * 16 + r] = f2bf(o[mi][di][r] * rinv[mi]);
  }
}

// ---------------- launcher ----------------
extern "C" void kernel_launch(void* const* d_in, const int* in_sizes, int n_in,
                              void* d_out, int out_size, void* d_ws, size_t ws_size,
                              hipStream_t stream) {
  const float* x    = (const float*)d_in[0];
  const float* rot  = (const float*)d_in[1];
  const float* Wq   = (const float*)d_in[2];
  const float* Wkv  = (const float*)d_in[3];
  const float* Wout = (const float*)d_in[4];
  const float* bout = (const float*)d_in[5];
  float* out = (float*)d_out;

  char* ws = (char*)d_ws;
  size_t off = 0;
  auto alloc = [&](size_t bytes) {
    void* p = ws + off;
    off = (off + bytes + 255) & ~(size_t)255;
    return p;
  };
  u16*    xb    = (u16*)alloc((size_t)MM * DD * 2);
  u16*    WT    = (u16*)alloc((size_t)QS * DD * 2);
  u16*    WoutT = (u16*)alloc((size_t)DD * DD * 2);
  float4* tab4  = (float4*)alloc((size_t)NN * 32 * 16);
  u16*    qdb   = (u16*)alloc((size_t)MM * DD * 2);
  u16*    kdb   = (u16*)alloc((size_t)MM * DD * 2);
  u16*    vtt   = (u16*)alloc((size_t)MM * DD * 2);
  u16*    ao    = (u16*)alloc((size_t)MM * DD * 2);

  cvt_kernel<<<(MM * DD / 4) / 256, 256, 0, stream>>>(x, xb, MM * DD);
  tcvt3_kernel<<<dim3(64, 16), 256, 0, stream>>>(Wq, Wkv, Wout, WT, WoutT);
  rope_tab_kernel<<<(NN * 32) / 256, 256, 0, stream>>>(rot, tab4);

  gemm_qkv<<<dim3(QS / 128, MM / 128), 256, 0, stream>>>(xb, WT, qdb, kdb, vtt, tab4);

  attn_kernel<<<dim3(NN / 256, BB * HH), 512, 0, stream>>>(qdb, kdb, vtt, ao);

  gemm_out<<<dim3(DD / 128, MM / 128), 256, 0, stream>>>(ao, WoutT, out, bout, MM, DD, DD);
}